// Round 10
// baseline (609.477 us; speedup 1.0000x reference)
//
#include <hip/hip_runtime.h>

#define D      128
#define NCLI   100000
#define NAGG   1000
#define NLAYER 3
#define NBKT   98    // coarse a2c buckets (dst>>10), 98*1024 >= 100000
#define NC2A   63    // coarse c2a buckets (bin>>7), 63*128 >= 8000
#define NRNG   8     // src ranges for c2a CSR (12500 clients each, 3.2 MB slice/XCD-L2)
#define NBIN   (NAGG * NRNG)   // 8000
#define RMAGIC 343598u         // ceil(2^32/12500): r = umulhi(src, RMAGIC), exact for src<100000
#define NHIST  512
#define NCVTX  (NCLI * D / 4 / 256)   // 12500
#define NCVTW  ((NLAYER * D * D + 255) / 256)  // 192
#define NROWT  (NCLI / 32)            // 3125 row-tiles (exact)
#define CPB    391    // clients per agg_big block (256 blocks x 391 >= 100000)

typedef short bf16x8 __attribute__((ext_vector_type(8)));
typedef float f32x16 __attribute__((ext_vector_type(16)));

static __device__ __forceinline__ float leaky(float x) { return x >= 0.f ? x : 0.1f * x; }

// ---- bf16 pack/unpack (RNE) ----
static __device__ __forceinline__ unsigned bf16_rn(float f) {
    unsigned u = __float_as_uint(f);
    return (u + 0x7fffu + ((u >> 16) & 1u)) >> 16;
}
static __device__ __forceinline__ float bf_val(unsigned h) { return __uint_as_float(h << 16); }
static __device__ __forceinline__ unsigned pack_bf2(float lo, float hi) {
    return bf16_rn(lo) | (bf16_rn(hi) << 16);
}
static __device__ __forceinline__ float bf_lo(unsigned v) { return __uint_as_float(v << 16); }
static __device__ __forceinline__ float bf_hi(unsigned v) { return __uint_as_float(v & 0xffff0000u); }

// ---------------- phase 1: hist + feature/weight cvt, one launch ----------------
__global__ __launch_bounds__(256) void prep(const int* __restrict__ c2a_src,
                                            const int* __restrict__ c2a_dst,
                                            const int* __restrict__ a2c_dst, int E,
                                            int* __restrict__ cnt_ar, int* __restrict__ bcnt,
                                            const float4* __restrict__ X4,
                                            uint2* __restrict__ xhi, uint2* __restrict__ xlo,
                                            const float* __restrict__ W,
                                            unsigned short* __restrict__ Wt) {
    __shared__ int h[NBIN + NBKT];   // 32.4 KB
    int bid = blockIdx.x;
    if (bid < NHIST) {
        for (int i = threadIdx.x; i < NBIN + NBKT; i += 256) h[i] = 0;
        __syncthreads();
        int stride = NHIST * 256;
        for (int e = bid * 256 + threadIdx.x; e < E; e += stride) {
            int s = c2a_src[e];
            int bin = c2a_dst[e] * NRNG + (int)__umulhi((unsigned)s, RMAGIC);
            atomicAdd(&h[bin], 1);
            atomicAdd(&h[NBIN + (a2c_dst[e] >> 10)], 1);
        }
        __syncthreads();
        for (int i = threadIdx.x; i < NBIN; i += 256)
            if (h[i]) atomicAdd(&cnt_ar[i], h[i]);
        for (int i = threadIdx.x; i < NBKT; i += 256)
            if (h[NBIN + i]) atomicAdd(&bcnt[i], h[NBIN + i]);
    } else if (bid < NHIST + NCVTX) {
        int t = (bid - NHIST) * 256 + threadIdx.x;
        float4 f = X4[t];
        unsigned h0 = bf16_rn(f.x), h1 = bf16_rn(f.y), h2 = bf16_rn(f.z), h3 = bf16_rn(f.w);
        xhi[t] = make_uint2(h0 | (h1 << 16), h2 | (h3 << 16));
        xlo[t] = make_uint2(pack_bf2(f.x - bf_val(h0), f.y - bf_val(h1)),
                            pack_bf2(f.z - bf_val(h2), f.w - bf_val(h3)));
    } else {
        int idx = (bid - NHIST - NCVTX) * 256 + threadIdx.x;
        if (idx >= NLAYER * D * D) return;
        int layer = idx >> 14, rem = idx & (D * D - 1);
        int k = rem >> 7, n = rem & 127;
        float w = W[layer * D * D + k * D + n];
        unsigned hh = bf16_rn(w);
        unsigned short* base = Wt + layer * 2 * D * D;
        base[n * D + k] = (unsigned short)hh;
        base[D * D + n * D + k] = (unsigned short)bf16_rn(w - bf_val(hh));
    }
}

// ---------------- phase 2: scans ----------------
__global__ void scan_both(const int* __restrict__ cnt_ar, int* __restrict__ rp_ar,
                          const int* __restrict__ bcnt,
                          int* __restrict__ brp, int* __restrict__ bcur,
                          int* __restrict__ ccur) {
    __shared__ int sh[1024];
    int t = threadIdx.x;
    if (blockIdx.x == 0) {
        int v[8];
        int s = 0;
#pragma unroll
        for (int j = 0; j < 8; j++) {
            int idx = t * 8 + j;
            v[j] = (idx < NBIN) ? cnt_ar[idx] : 0;
            s += v[j];
        }
        sh[t] = s;
        __syncthreads();
        for (int off = 1; off < 1024; off <<= 1) {
            int x = (t >= off) ? sh[t - off] : 0;
            __syncthreads();
            sh[t] += x;
            __syncthreads();
        }
        int run = sh[t] - s;  // exclusive prefix of this thread's chunk
#pragma unroll
        for (int j = 0; j < 8; j++) {
            int idx = t * 8 + j;
            if (idx < NBIN) rp_ar[idx] = run;
            run += v[j];
        }
        if (t == 1023) rp_ar[NBIN] = sh[1023];
        __syncthreads();   // drains global writes before cross-thread read
        if (t < NC2A) ccur[t] = rp_ar[t * 128];
    } else {
        int v = (t < NBKT) ? bcnt[t] : 0;
        sh[t] = v;
        __syncthreads();
        for (int off = 1; off < 1024; off <<= 1) {
            int x = (t >= off) ? sh[t - off] : 0;
            __syncthreads();
            sh[t] += x;
            __syncthreads();
        }
        if (t == 0) { brp[0] = 0; bcur[0] = 0; }
        if (t < NBKT) {
            brp[t + 1] = sh[t];
            if (t + 1 < NBKT) bcur[t + 1] = sh[t];
        }
    }
}

// ---------------- phase 3: pass A — coarse scatter (block-private contiguous runs) ----
__global__ __launch_bounds__(1024) void scatter_coarse(const int* __restrict__ c2a_src,
                                                       const int* __restrict__ c2a_dst,
                                                       const int* __restrict__ a2c_src,
                                                       const int* __restrict__ a2c_dst, int E,
                                                       int* __restrict__ ccur,
                                                       int* __restrict__ tmp1,
                                                       int* __restrict__ bcur,
                                                       int* __restrict__ tmp2) {
    __shared__ int h[NBKT], base[NBKT];
    int tid = threadIdx.x;
    if (blockIdx.x < 256) {
        int chunk = (E + 255) / 256;
        int e0 = blockIdx.x * chunk;
        int e1 = min(E, e0 + chunk);
        for (int i = tid; i < NC2A; i += 1024) h[i] = 0;
        __syncthreads();
        for (int e = e0 + tid; e < e1; e += 1024) {
            int s = c2a_src[e];
            int bin = c2a_dst[e] * NRNG + (int)__umulhi((unsigned)s, RMAGIC);
            atomicAdd(&h[bin >> 7], 1);
        }
        __syncthreads();
        for (int i = tid; i < NC2A; i += 1024) {
            int c = h[i];
            base[i] = c ? atomicAdd(&ccur[i], c) : 0;
        }
        __syncthreads();
        for (int e = e0 + tid; e < e1; e += 1024) {
            int s = c2a_src[e];
            int bin = c2a_dst[e] * NRNG + (int)__umulhi((unsigned)s, RMAGIC);
            int pos = atomicAdd(&base[bin >> 7], 1);
            tmp1[pos] = (bin << 17) | s;
        }
    } else {
        int bid = blockIdx.x - 256;
        int chunk = (E + 255) / 256;
        int e0 = bid * chunk;
        int e1 = min(E, e0 + chunk);
        for (int i = tid; i < NBKT; i += 1024) h[i] = 0;
        __syncthreads();
        for (int e = e0 + tid; e < e1; e += 1024) atomicAdd(&h[a2c_dst[e] >> 10], 1);
        __syncthreads();
        for (int i = tid; i < NBKT; i += 1024) {
            int c = h[i];
            base[i] = c ? atomicAdd(&bcur[i], c) : 0;
        }
        __syncthreads();
        for (int e = e0 + tid; e < e1; e += 1024) {
            int d = a2c_dst[e];
            int pos = atomicAdd(&base[d >> 10], 1);
            tmp2[pos] = ((d & 1023) << 10) | a2c_src[e];
        }
    }
}

// ---------------- phase 4: pass B — refine within coarse buckets ----------------
__global__ __launch_bounds__(1024) void refine(const int* __restrict__ rp_ar,
                                               const int* __restrict__ tmp1,
                                               int* __restrict__ col_c2a,
                                               const int* __restrict__ brp,
                                               const int* __restrict__ tmp2,
                                               int* __restrict__ rp_c,
                                               int* __restrict__ col_a2c) {
    int tid = threadIdx.x;
    if (blockIdx.x < NC2A) {
        __shared__ int lcur[128];
        int c = blockIdx.x;
        int b0 = c * 128;
        int nb = min(128, NBIN - b0);
        if (tid < nb) lcur[tid] = rp_ar[b0 + tid];
        int beg = rp_ar[b0];
        int end = rp_ar[min(b0 + 128, NBIN)];
        __syncthreads();
        for (int e = beg + tid; e < end; e += 1024) {
            int v = tmp1[e];
            int pos = atomicAdd(&lcur[(v >> 17) - b0], 1);
            col_c2a[pos] = v & 0x1FFFF;
        }
    } else {
        __shared__ int h2[1024], cur2[1024];
        int b = blockIdx.x - NC2A;
        int beg = brp[b], end = brp[b + 1];
        h2[tid] = 0;
        __syncthreads();
        for (int e = beg + tid; e < end; e += 1024) atomicAdd(&h2[tmp2[e] >> 10], 1);
        __syncthreads();
        cur2[tid] = h2[tid];
        __syncthreads();
        for (int off = 1; off < 1024; off <<= 1) {
            int x = (tid >= off) ? cur2[tid - off] : 0;
            __syncthreads();
            cur2[tid] += x;
            __syncthreads();
        }
        int start = beg + cur2[tid] - h2[tid];
        int c = b * 1024 + tid;
        if (c < NCLI) rp_c[c] = start;
        cur2[tid] = start;
        if (b == NBKT - 1 && tid == 0) rp_c[NCLI] = end;
        __syncthreads();
        for (int e = beg + tid; e < end; e += 1024) {
            int p = tmp2[e];
            int pos = atomicAdd(&cur2[p >> 10], 1);
            col_a2c[pos] = p & 1023;
        }
    }
}

// ---------------- layer kernels ----------------

// XCD-sliced mean gather (unchanged). NOT launched for the last layer (xa dead).
__global__ __launch_bounds__(512) void gather_mean(const unsigned* __restrict__ tbl,
                                                   const int* __restrict__ rp_ar,
                                                   const int* __restrict__ col,
                                                   float* __restrict__ psum) {
    __shared__ float part[4][8][D];   // 16 KB
    int quad = blockIdx.x >> 3, r = blockIdx.x & 7;
    int tid = threadIdx.x;
    int a = tid >> 7;            // local agg 0..3
    int sub = (tid >> 4) & 7;    // reader 0..7
    int sl = tid & 15;           // lane in reader
    const uint4* tbl4 = (const uint4*)tbl;
    int agg = quad * 4 + a;
    int bin = agg * NRNG + r;
    int beg = rp_ar[bin], end = rp_ar[bin + 1];
    float f0 = 0, f1 = 0, f2 = 0, f3 = 0, f4 = 0, f5 = 0, f6 = 0, f7 = 0;
    int e = beg + sub;
    for (; e + 8 < end; e += 16) {   // 2 edges in flight per reader
        int s0 = col[e];
        int s1 = col[e + 8];
        uint4 v0 = tbl4[(s0 << 4) + sl];
        uint4 v1 = tbl4[(s1 << 4) + sl];
        f0 += bf_lo(v0.x); f1 += bf_hi(v0.x); f2 += bf_lo(v0.y); f3 += bf_hi(v0.y);
        f4 += bf_lo(v0.z); f5 += bf_hi(v0.z); f6 += bf_lo(v0.w); f7 += bf_hi(v0.w);
        f0 += bf_lo(v1.x); f1 += bf_hi(v1.x); f2 += bf_lo(v1.y); f3 += bf_hi(v1.y);
        f4 += bf_lo(v1.z); f5 += bf_hi(v1.z); f6 += bf_lo(v1.w); f7 += bf_hi(v1.w);
    }
    if (e < end) {
        int s0 = col[e];
        uint4 v0 = tbl4[(s0 << 4) + sl];
        f0 += bf_lo(v0.x); f1 += bf_hi(v0.x); f2 += bf_lo(v0.y); f3 += bf_hi(v0.y);
        f4 += bf_lo(v0.z); f5 += bf_hi(v0.z); f6 += bf_lo(v0.w); f7 += bf_hi(v0.w);
    }
    float* pr = &part[a][sub][sl * 8];
    pr[0] = f0; pr[1] = f1; pr[2] = f2; pr[3] = f3;
    pr[4] = f4; pr[5] = f5; pr[6] = f6; pr[7] = f7;
    __syncthreads();
    int c = tid & 127;
    float s = 0.f;
#pragma unroll
    for (int g = 0; g < 8; g++) s += part[a][g][c];
    psum[((size_t)agg * NRNG + r) * D + c] = s;
}

// combine partials -> mean; ya = xa@Wl_a2c (bf16); xa_new = leaky(...).
// LAST=1: final layer's xa is DEAD -> compute only ya.
template <int LAST>
__global__ __launch_bounds__(128) void combine_agg(const float* __restrict__ psum,
                                                   const int* __restrict__ rp_ar,
                                                   const float* xa_old,
                                                   const float* __restrict__ Wl_a2c,
                                                   const float* __restrict__ Wl_c2a,
                                                   const float* __restrict__ Wr_c2a,
                                                   const float* __restrict__ b_c2a,
                                                   unsigned short* __restrict__ ya_bf,
                                                   float* xa_out) {
    __shared__ float mr[D], xr[D];
    int i = blockIdx.x, j = threadIdx.x;
    if (LAST) {
        xr[j] = xa_old[i * D + j];
        __syncthreads();
        float accy = 0.f;
#pragma unroll 4
        for (int k = 0; k < D; k++) accy += xr[k] * Wl_a2c[k * D + j];
        ya_bf[i * D + j] = (unsigned short)bf16_rn(accy);
        return;
    }
    const float* pr = psum + (size_t)i * NRNG * D + j;
    float s = 0.f;
#pragma unroll
    for (int r = 0; r < NRNG; r++) s += pr[r * D];
    int deg = rp_ar[i * NRNG + NRNG] - rp_ar[i * NRNG];
    mr[j] = s / fmaxf((float)deg, 1.f);
    xr[j] = xa_old[i * D + j];
    __syncthreads();
    float accy = 0.f, accn = b_c2a[j];
#pragma unroll 4
    for (int k = 0; k < D; k++) {
        accy += xr[k] * Wl_a2c[k * D + j];
        accn += mr[k] * Wl_c2a[k * D + j] + xr[k] * Wr_c2a[k * D + j];
    }
    ya_bf[i * D + j] = (unsigned short)bf16_rn(accy);
    xa_out[i * D + j] = leaky(accn);
}

// R10a: pure gemm, Y = xc @ W + bias -> Yb (f32). No LDS, streamed A/B, direct
// per-reg stores (2x128B segments per instr). Lean VGPR -> high occupancy.
__global__ __launch_bounds__(256) void gemm_y(const unsigned short* __restrict__ Ahi,
                                              const unsigned short* __restrict__ Alo,
                                              const unsigned short* __restrict__ Wt,
                                              const float* __restrict__ bias,
                                              float* __restrict__ Yb) {
    int tid = threadIdx.x;
    int wave = tid >> 6, lane = tid & 63;
    int cl = lane & 31, kh = lane >> 5;
    int n0 = wave * 32;
    int m0 = blockIdx.x * 32;
    float bv = bias[n0 + cl];
    f32x16 acc;
#pragma unroll
    for (int qq = 0; qq < 16; qq++) acc[qq] = bv;
    {
        const unsigned short* Wlo_ = Wt + D * D;
        const unsigned short* ar = Ahi + (size_t)(m0 + cl) * D + kh * 8;
        const unsigned short* al = Alo + (size_t)(m0 + cl) * D + kh * 8;
        const unsigned short* wh = Wt + (size_t)(n0 + cl) * D + kh * 8;
        const unsigned short* wl = Wlo_ + (size_t)(n0 + cl) * D + kh * 8;
#pragma unroll
        for (int kc = 0; kc < 8; kc++) {
            bf16x8 ahi = *(const bf16x8*)(ar + kc * 16);
            bf16x8 alo = *(const bf16x8*)(al + kc * 16);
            bf16x8 bh = *(const bf16x8*)(wh + kc * 16);
            bf16x8 bl = *(const bf16x8*)(wl + kc * 16);
            acc = __builtin_amdgcn_mfma_f32_32x32x16_bf16(ahi, bh, acc, 0, 0, 0);
            acc = __builtin_amdgcn_mfma_f32_32x32x16_bf16(alo, bh, acc, 0, 0, 0);
            acc = __builtin_amdgcn_mfma_f32_32x32x16_bf16(ahi, bl, acc, 0, 0, 0);
        }
    }
    float* yb = Yb + (size_t)m0 * D + n0 + cl;
#pragma unroll
    for (int reg = 0; reg < 16; reg++) {
        int row = (reg & 3) + 8 * (reg >> 2) + 4 * kh;
        yb[(size_t)row * D] = acc[reg];
    }
}

// R10b: agg with LDS-STAGED ya. The R2-R7 plateau (90-178us) was L2 request
// saturation: per-edge random reads of the 256KB ya table = 410MB/layer of
// 4-line granules. Here 256 blocks x 391 clients stage HALF of ya (128KB,
// row-padded to 144B) in LDS per pass; 2 dim-half passes. Chip ya traffic
// 410MB random -> 64MB sequential. 8-lane groups, lane q owns dims h*64+8q..+8;
// per-dim add order identical to R9 -> bit-identical output.
template <int LAST>
__global__ __launch_bounds__(1024) void agg_big(const unsigned short* __restrict__ ya,
                                                const int* __restrict__ rowptr,
                                                const int* __restrict__ col,
                                                const float* __restrict__ Yb,
                                                unsigned* __restrict__ xhi,
                                                unsigned* __restrict__ xlo,
                                                const float* __restrict__ Wlin,
                                                const float* __restrict__ blin,
                                                float* __restrict__ out) {
    __shared__ uint4 yast4[NAGG * 9];   // 144000 B: 1000 rows x (8 data + 1 pad) uint4
    int tid = threadIdx.x;
    int wave = tid >> 6, lane = tid & 63;
    int g = lane >> 3, q = lane & 7;    // 8 groups of 8 lanes per wave
    int m0 = blockIdx.x * CPB;
    const uint4* ya4g = (const uint4*)ya;   // 16 uint4 per row
    float dacc[4] = {0.f, 0.f, 0.f, 0.f};  // LAST partial dots, live across passes
#pragma unroll
    for (int h = 0; h < 2; h++) {
        if (h) __syncthreads();   // all waves done reading pass-0 LDS
        // stage half h: 8000 uint4, sequential from L2
        for (int i = tid; i < NAGG * 8; i += 1024) {
            int row = i >> 3, qq = i & 7;
            yast4[row * 9 + qq] = ya4g[(row << 4) + (h << 3) + qq];
        }
        __syncthreads();
#pragma unroll
        for (int cc = 0; cc < 4; cc++) {
            int c_local = (wave * 8 + g) * 4 + cc;   // 0..511
            int gid = m0 + c_local;
            bool act = (c_local < CPB) && (gid < NCLI);
            int beg = 0, end = 0;
            if (act) { beg = rowptr[gid]; end = rowptr[gid + 1]; }
            float s0 = 0, s1 = 0, s2 = 0, s3 = 0, s4 = 0, s5 = 0, s6 = 0, s7 = 0;
            for (int ch = beg; ch < end; ch += 8) {
                int ec = col[min(ch + q, end - 1)];
                int lim = min(8, end - ch);
#pragma unroll
                for (int j = 0; j < 8; j++) {
                    if (j < lim) {
                        int r = __shfl(ec, j, 8);
                        uint4 v = yast4[r * 9 + q];
                        s0 += bf_lo(v.x); s1 += bf_hi(v.x);
                        s2 += bf_lo(v.y); s3 += bf_hi(v.y);
                        s4 += bf_lo(v.z); s5 += bf_hi(v.z);
                        s6 += bf_lo(v.w); s7 += bf_hi(v.w);
                    }
                }
            }
            if (act) {
                float inv = 1.f / fmaxf((float)(end - beg), 1.f);
                const float4* yb4 =
                    (const float4*)(Yb + (size_t)gid * D + h * 64 + q * 8);
                float4 y0 = yb4[0], y1 = yb4[1];
                float r0 = leaky(y0.x + s0 * inv);
                float r1 = leaky(y0.y + s1 * inv);
                float r2 = leaky(y0.z + s2 * inv);
                float r3 = leaky(y0.w + s3 * inv);
                float r4 = leaky(y1.x + s4 * inv);
                float r5 = leaky(y1.y + s5 * inv);
                float r6 = leaky(y1.z + s6 * inv);
                float r7 = leaky(y1.w + s7 * inv);
                if (LAST) {
                    float4 w0 = *(const float4*)&Wlin[h * 64 + q * 8];
                    float4 w1 = *(const float4*)&Wlin[h * 64 + q * 8 + 4];
                    dacc[cc] += r0 * w0.x + r1 * w0.y + r2 * w0.z + r3 * w0.w +
                                r4 * w1.x + r5 * w1.y + r6 * w1.z + r7 * w1.w;
                    if (h == 1) {
                        float v = dacc[cc];
#pragma unroll
                        for (int off = 4; off > 0; off >>= 1) v += __shfl_down(v, off, 8);
                        if (q == 0) out[gid] = v + blin[0];
                    }
                } else {
                    unsigned h0 = bf16_rn(r0), h1 = bf16_rn(r1);
                    unsigned h2 = bf16_rn(r2), h3 = bf16_rn(r3);
                    unsigned h4 = bf16_rn(r4), h5 = bf16_rn(r5);
                    unsigned h6 = bf16_rn(r6), h7 = bf16_rn(r7);
                    uint4 hi, lo;
                    hi.x = h0 | (h1 << 16); hi.y = h2 | (h3 << 16);
                    hi.z = h4 | (h5 << 16); hi.w = h6 | (h7 << 16);
                    lo.x = pack_bf2(r0 - bf_val(h0), r1 - bf_val(h1));
                    lo.y = pack_bf2(r2 - bf_val(h2), r3 - bf_val(h3));
                    lo.z = pack_bf2(r4 - bf_val(h4), r5 - bf_val(h5));
                    lo.w = pack_bf2(r6 - bf_val(h6), r7 - bf_val(h7));
                    ((uint4*)xhi)[(gid << 4) + (h << 3) + q] = hi;
                    ((uint4*)xlo)[(gid << 4) + (h << 3) + q] = lo;
                }
            }
        }
    }
}

extern "C" void kernel_launch(void* const* d_in, const int* in_sizes, int n_in,
                              void* d_out, int out_size, void* d_ws, size_t ws_size,
                              hipStream_t stream) {
    const float* x_clients = (const float*)d_in[0];
    const float* x_agg     = (const float*)d_in[1];
    const int*   c2a_src   = (const int*)d_in[2];
    const int*   c2a_dst   = (const int*)d_in[3];
    const int*   a2c_src   = (const int*)d_in[4];
    const int*   a2c_dst   = (const int*)d_in[5];
    const float* Wl_c2a    = (const float*)d_in[6];
    const float* Wr_c2a    = (const float*)d_in[7];
    const float* b_c2a     = (const float*)d_in[8];
    const float* Wl_a2c    = (const float*)d_in[9];
    const float* Wr_a2c    = (const float*)d_in[10];
    const float* b_a2c     = (const float*)d_in[11];
    const float* W_lin     = (const float*)d_in[12];
    const float* b_lin     = (const float*)d_in[13];
    float* out = (float*)d_out;
    const int E = in_sizes[2];

    char* p = (char*)d_ws;
    auto alloc = [&](size_t bytes) {
        char* r = p;
        p += (bytes + 255) & ~(size_t)255;
        return r;
    };
    float*    Yb    = (float*)alloc(sizeof(float) * NCLI * D);         // gemm out; tmp1/2 early
    unsigned* xc_hi = (unsigned*)alloc(sizeof(unsigned) * NCLI * 64);  // bf16 hi (also gather tbl)
    unsigned* xc_lo = (unsigned*)alloc(sizeof(unsigned) * NCLI * 64);  // bf16 lo
    float*    xa    = (float*)alloc(sizeof(float) * NAGG * D);
    unsigned short* ya_bf = (unsigned short*)alloc(sizeof(unsigned short) * NAGG * D);
    unsigned short* Wt = (unsigned short*)alloc(sizeof(unsigned short) * NLAYER * 2 * D * D);
    float* psum  = (float*)alloc(sizeof(float) * NAGG * NRNG * D);     // 4 MB gather partials
    int* cnt_ar = (int*)alloc(sizeof(int) * (NBIN + NBKT));  // cnt_ar[0..7999] + bcnt
    int* bcnt  = cnt_ar + NBIN;
    int* rp_ar = (int*)alloc(sizeof(int) * (NBIN + 1));
    int* brp   = (int*)alloc(sizeof(int) * (NBKT + 1));
    int* bcur  = (int*)alloc(sizeof(int) * NBKT);
    int* ccur  = (int*)alloc(sizeof(int) * NC2A);
    int* rp_c  = (int*)alloc(sizeof(int) * (NCLI + 1));
    int* col_c2a = (int*)alloc(sizeof(int) * E);
    int* col_a2c = (int*)alloc(sizeof(int) * E);
    // tmp1/tmp2 alias Yb (12.8 MB needed, 51.2 MB available); lifetime ends before layers
    int* tmp1 = (int*)Yb;
    int* tmp2 = tmp1 + E;

    hipMemsetAsync(cnt_ar, 0, sizeof(int) * (NBIN + NBKT), stream);

    prep<<<NHIST + NCVTX + NCVTW, 256, 0, stream>>>(c2a_src, c2a_dst, a2c_dst, E, cnt_ar, bcnt,
                                                    (const float4*)x_clients,
                                                    (uint2*)xc_hi, (uint2*)xc_lo,
                                                    Wr_a2c, Wt);
    scan_both<<<2, 1024, 0, stream>>>(cnt_ar, rp_ar, bcnt, brp, bcur, ccur);
    scatter_coarse<<<512, 1024, 0, stream>>>(c2a_src, c2a_dst, a2c_src, a2c_dst, E,
                                             ccur, tmp1, bcur, tmp2);
    refine<<<NC2A + NBKT, 1024, 0, stream>>>(rp_ar, tmp1, col_c2a, brp, tmp2, rp_c, col_a2c);

    const float* xa_old = x_agg;
    for (int l = 0; l < NLAYER; l++) {
        if (l < NLAYER - 1) {
            gather_mean<<<(NAGG / 4) * NRNG, 512, 0, stream>>>(xc_hi, rp_ar, col_c2a, psum);
            combine_agg<0><<<NAGG, 128, 0, stream>>>(psum, rp_ar, xa_old,
                                                     Wl_a2c + l * D * D, Wl_c2a + l * D * D,
                                                     Wr_c2a + l * D * D, b_c2a + l * D,
                                                     ya_bf, xa);
            gemm_y<<<NROWT, 256, 0, stream>>>(
                (const unsigned short*)xc_hi, (const unsigned short*)xc_lo,
                Wt + l * 2 * D * D, b_a2c + l * D, Yb);
            agg_big<0><<<256, 1024, 0, stream>>>(ya_bf, rp_c, col_a2c, Yb,
                                                 xc_hi, xc_lo, nullptr, nullptr, nullptr);
        } else {
            combine_agg<1><<<NAGG, 128, 0, stream>>>(psum, rp_ar, xa_old,
                                                     Wl_a2c + l * D * D, Wl_c2a + l * D * D,
                                                     Wr_c2a + l * D * D, b_c2a + l * D,
                                                     ya_bf, xa);
            gemm_y<<<NROWT, 256, 0, stream>>>(
                (const unsigned short*)xc_hi, (const unsigned short*)xc_lo,
                Wt + l * 2 * D * D, b_a2c + l * D, Yb);
            agg_big<1><<<256, 1024, 0, stream>>>(ya_bf, rp_c, col_a2c, Yb,
                                                 nullptr, nullptr, W_lin, b_lin, out);
        }
        xa_old = xa;
    }
}

// Round 11
// 604.580 us; speedup vs baseline: 1.0081x; 1.0081x over previous
//
#include <hip/hip_runtime.h>

#define D      128
#define NCLI   100000
#define NAGG   1000
#define NLAYER 3
#define NBKT   98    // coarse a2c buckets (dst>>10), 98*1024 >= 100000
#define NC2A   63    // coarse c2a buckets (bin>>7), 63*128 >= 8000
#define NRNG   8     // src ranges for c2a CSR (12500 clients each, 3.2 MB slice/XCD-L2)
#define NBIN   (NAGG * NRNG)   // 8000
#define RMAGIC 343598u         // ceil(2^32/12500): r = umulhi(src, RMAGIC), exact for src<100000
#define NHIST  512
#define NCVTX  (NCLI * D / 4 / 256)   // 12500
#define NCVTW  ((NLAYER * D * D + 255) / 256)  // 192
#define NROWT  (NCLI / 32)            // 3125 row-tiles (exact)
#define NGEMM  ((NROWT + 1) / 2)      // 1563 gemm blocks (2 tiles each)
#define NGATH  ((NAGG / 4) * NRNG)    // 2000 gather blocks
#define NLAST  (NAGG / 4)             // 250 combine-last blocks
#define CPB    391    // clients per agg_big block (256 blocks x 391 >= 100000)

typedef short bf16x8 __attribute__((ext_vector_type(8)));
typedef float f32x16 __attribute__((ext_vector_type(16)));

static __device__ __forceinline__ float leaky(float x) { return x >= 0.f ? x : 0.1f * x; }

// ---- bf16 pack/unpack (RNE) ----
static __device__ __forceinline__ unsigned bf16_rn(float f) {
    unsigned u = __float_as_uint(f);
    return (u + 0x7fffu + ((u >> 16) & 1u)) >> 16;
}
static __device__ __forceinline__ float bf_val(unsigned h) { return __uint_as_float(h << 16); }
static __device__ __forceinline__ unsigned pack_bf2(float lo, float hi) {
    return bf16_rn(lo) | (bf16_rn(hi) << 16);
}
static __device__ __forceinline__ float bf_lo(unsigned v) { return __uint_as_float(v << 16); }
static __device__ __forceinline__ float bf_hi(unsigned v) { return __uint_as_float(v & 0xffff0000u); }

// ---------------- phase 1: hist + feature/weight cvt, one launch ----------------
__global__ __launch_bounds__(256) void prep(const int* __restrict__ c2a_src,
                                            const int* __restrict__ c2a_dst,
                                            const int* __restrict__ a2c_dst, int E,
                                            int* __restrict__ cnt_ar, int* __restrict__ bcnt,
                                            const float4* __restrict__ X4,
                                            uint2* __restrict__ xhi, uint2* __restrict__ xlo,
                                            const float* __restrict__ W,
                                            unsigned short* __restrict__ Wt) {
    __shared__ int h[NBIN + NBKT];   // 32.4 KB
    int bid = blockIdx.x;
    if (bid < NHIST) {
        for (int i = threadIdx.x; i < NBIN + NBKT; i += 256) h[i] = 0;
        __syncthreads();
        int stride = NHIST * 256;
        for (int e = bid * 256 + threadIdx.x; e < E; e += stride) {
            int s = c2a_src[e];
            int bin = c2a_dst[e] * NRNG + (int)__umulhi((unsigned)s, RMAGIC);
            atomicAdd(&h[bin], 1);
            atomicAdd(&h[NBIN + (a2c_dst[e] >> 10)], 1);
        }
        __syncthreads();
        for (int i = threadIdx.x; i < NBIN; i += 256)
            if (h[i]) atomicAdd(&cnt_ar[i], h[i]);
        for (int i = threadIdx.x; i < NBKT; i += 256)
            if (h[NBIN + i]) atomicAdd(&bcnt[i], h[NBIN + i]);
    } else if (bid < NHIST + NCVTX) {
        int t = (bid - NHIST) * 256 + threadIdx.x;
        float4 f = X4[t];
        unsigned h0 = bf16_rn(f.x), h1 = bf16_rn(f.y), h2 = bf16_rn(f.z), h3 = bf16_rn(f.w);
        xhi[t] = make_uint2(h0 | (h1 << 16), h2 | (h3 << 16));
        xlo[t] = make_uint2(pack_bf2(f.x - bf_val(h0), f.y - bf_val(h1)),
                            pack_bf2(f.z - bf_val(h2), f.w - bf_val(h3)));
    } else {
        int idx = (bid - NHIST - NCVTX) * 256 + threadIdx.x;
        if (idx >= NLAYER * D * D) return;
        int layer = idx >> 14, rem = idx & (D * D - 1);
        int k = rem >> 7, n = rem & 127;
        float w = W[layer * D * D + k * D + n];
        unsigned hh = bf16_rn(w);
        unsigned short* base = Wt + layer * 2 * D * D;
        base[n * D + k] = (unsigned short)hh;
        base[D * D + n * D + k] = (unsigned short)bf16_rn(w - bf_val(hh));
    }
}

// ---------------- phase 2: scans ----------------
__global__ void scan_both(const int* __restrict__ cnt_ar, int* __restrict__ rp_ar,
                          const int* __restrict__ bcnt,
                          int* __restrict__ brp, int* __restrict__ bcur,
                          int* __restrict__ ccur) {
    __shared__ int sh[1024];
    int t = threadIdx.x;
    if (blockIdx.x == 0) {
        int v[8];
        int s = 0;
#pragma unroll
        for (int j = 0; j < 8; j++) {
            int idx = t * 8 + j;
            v[j] = (idx < NBIN) ? cnt_ar[idx] : 0;
            s += v[j];
        }
        sh[t] = s;
        __syncthreads();
        for (int off = 1; off < 1024; off <<= 1) {
            int x = (t >= off) ? sh[t - off] : 0;
            __syncthreads();
            sh[t] += x;
            __syncthreads();
        }
        int run = sh[t] - s;  // exclusive prefix of this thread's chunk
#pragma unroll
        for (int j = 0; j < 8; j++) {
            int idx = t * 8 + j;
            if (idx < NBIN) rp_ar[idx] = run;
            run += v[j];
        }
        if (t == 1023) rp_ar[NBIN] = sh[1023];
        __syncthreads();   // drains global writes before cross-thread read
        if (t < NC2A) ccur[t] = rp_ar[t * 128];
    } else {
        int v = (t < NBKT) ? bcnt[t] : 0;
        sh[t] = v;
        __syncthreads();
        for (int off = 1; off < 1024; off <<= 1) {
            int x = (t >= off) ? sh[t - off] : 0;
            __syncthreads();
            sh[t] += x;
            __syncthreads();
        }
        if (t == 0) { brp[0] = 0; bcur[0] = 0; }
        if (t < NBKT) {
            brp[t + 1] = sh[t];
            if (t + 1 < NBKT) bcur[t + 1] = sh[t];
        }
    }
}

// ---------------- phase 3: pass A — coarse scatter (block-private contiguous runs) ----
__global__ __launch_bounds__(1024) void scatter_coarse(const int* __restrict__ c2a_src,
                                                       const int* __restrict__ c2a_dst,
                                                       const int* __restrict__ a2c_src,
                                                       const int* __restrict__ a2c_dst, int E,
                                                       int* __restrict__ ccur,
                                                       int* __restrict__ tmp1,
                                                       int* __restrict__ bcur,
                                                       int* __restrict__ tmp2) {
    __shared__ int h[NBKT], base[NBKT];
    int tid = threadIdx.x;
    if (blockIdx.x < 256) {
        int chunk = (E + 255) / 256;
        int e0 = blockIdx.x * chunk;
        int e1 = min(E, e0 + chunk);
        for (int i = tid; i < NC2A; i += 1024) h[i] = 0;
        __syncthreads();
        for (int e = e0 + tid; e < e1; e += 1024) {
            int s = c2a_src[e];
            int bin = c2a_dst[e] * NRNG + (int)__umulhi((unsigned)s, RMAGIC);
            atomicAdd(&h[bin >> 7], 1);
        }
        __syncthreads();
        for (int i = tid; i < NC2A; i += 1024) {
            int c = h[i];
            base[i] = c ? atomicAdd(&ccur[i], c) : 0;
        }
        __syncthreads();
        for (int e = e0 + tid; e < e1; e += 1024) {
            int s = c2a_src[e];
            int bin = c2a_dst[e] * NRNG + (int)__umulhi((unsigned)s, RMAGIC);
            int pos = atomicAdd(&base[bin >> 7], 1);
            tmp1[pos] = (bin << 17) | s;
        }
    } else {
        int bid = blockIdx.x - 256;
        int chunk = (E + 255) / 256;
        int e0 = bid * chunk;
        int e1 = min(E, e0 + chunk);
        for (int i = tid; i < NBKT; i += 1024) h[i] = 0;
        __syncthreads();
        for (int e = e0 + tid; e < e1; e += 1024) atomicAdd(&h[a2c_dst[e] >> 10], 1);
        __syncthreads();
        for (int i = tid; i < NBKT; i += 1024) {
            int c = h[i];
            base[i] = c ? atomicAdd(&bcur[i], c) : 0;
        }
        __syncthreads();
        for (int e = e0 + tid; e < e1; e += 1024) {
            int d = a2c_dst[e];
            int pos = atomicAdd(&base[d >> 10], 1);
            tmp2[pos] = ((d & 1023) << 10) | a2c_src[e];
        }
    }
}

// ---------------- phase 4: pass B — refine within coarse buckets ----------------
__global__ __launch_bounds__(1024) void refine(const int* __restrict__ rp_ar,
                                               const int* __restrict__ tmp1,
                                               int* __restrict__ col_c2a,
                                               const int* __restrict__ brp,
                                               const int* __restrict__ tmp2,
                                               int* __restrict__ rp_c,
                                               int* __restrict__ col_a2c) {
    int tid = threadIdx.x;
    if (blockIdx.x < NC2A) {
        __shared__ int lcur[128];
        int c = blockIdx.x;
        int b0 = c * 128;
        int nb = min(128, NBIN - b0);
        if (tid < nb) lcur[tid] = rp_ar[b0 + tid];
        int beg = rp_ar[b0];
        int end = rp_ar[min(b0 + 128, NBIN)];
        __syncthreads();
        for (int e = beg + tid; e < end; e += 1024) {
            int v = tmp1[e];
            int pos = atomicAdd(&lcur[(v >> 17) - b0], 1);
            col_c2a[pos] = v & 0x1FFFF;
        }
    } else {
        __shared__ int h2[1024], cur2[1024];
        int b = blockIdx.x - NC2A;
        int beg = brp[b], end = brp[b + 1];
        h2[tid] = 0;
        __syncthreads();
        for (int e = beg + tid; e < end; e += 1024) atomicAdd(&h2[tmp2[e] >> 10], 1);
        __syncthreads();
        cur2[tid] = h2[tid];
        __syncthreads();
        for (int off = 1; off < 1024; off <<= 1) {
            int x = (tid >= off) ? cur2[tid - off] : 0;
            __syncthreads();
            cur2[tid] += x;
            __syncthreads();
        }
        int start = beg + cur2[tid] - h2[tid];
        int c = b * 1024 + tid;
        if (c < NCLI) rp_c[c] = start;
        cur2[tid] = start;
        if (b == NBKT - 1 && tid == 0) rp_c[NCLI] = end;
        __syncthreads();
        for (int e = beg + tid; e < end; e += 1024) {
            int p = tmp2[e];
            int pos = atomicAdd(&cur2[p >> 10], 1);
            col_a2c[pos] = p & 1023;
        }
    }
}

// ---------------- layer kernels ----------------

// combine partials -> mean; ya = xa@Wl_a2c (bf16); xa_new = leaky(...). (l<2 only)
__global__ __launch_bounds__(128) void combine_agg(const float* __restrict__ psum,
                                                   const int* __restrict__ rp_ar,
                                                   const float* xa_old,
                                                   const float* __restrict__ Wl_a2c,
                                                   const float* __restrict__ Wl_c2a,
                                                   const float* __restrict__ Wr_c2a,
                                                   const float* __restrict__ b_c2a,
                                                   unsigned short* __restrict__ ya_bf,
                                                   float* xa_out) {
    __shared__ float mr[D], xr[D];
    int i = blockIdx.x, j = threadIdx.x;
    const float* pr = psum + (size_t)i * NRNG * D + j;
    float s = 0.f;
#pragma unroll
    for (int r = 0; r < NRNG; r++) s += pr[r * D];
    int deg = rp_ar[i * NRNG + NRNG] - rp_ar[i * NRNG];
    mr[j] = s / fmaxf((float)deg, 1.f);
    xr[j] = xa_old[i * D + j];
    __syncthreads();
    float accy = 0.f, accn = b_c2a[j];
#pragma unroll 4
    for (int k = 0; k < D; k++) {
        accy += xr[k] * Wl_a2c[k * D + j];
        accn += mr[k] * Wl_c2a[k * D + j] + xr[k] * Wr_c2a[k * D + j];
    }
    ya_bf[i * D + j] = (unsigned short)bf16_rn(accy);
    xa_out[i * D + j] = leaky(accn);
}

// R11: MERGED per-layer parallel kernel. gemm_y(l) and gather_mean(l) depend only
// on xc(l-1) -> fully independent, but ran serially (56+50us, both latency-bound
// with all pipes idle). Streams/events are forbidden (graph capture), so overlap
// via block-range split in ONE launch (the prep/scatter trick): blocks [0,NGEMM)
// do two 32-row gemm tiles each (no barriers -> 2 sub-blocks safe), [NGEMM,+ngath)
// run the gather body, remainder (last layer only) runs combine<1> (4 aggs/block;
// independent of gemm: needs xa, gemm needs xc).
__global__ __launch_bounds__(512) void layer_par(
    const unsigned short* __restrict__ Ahi, const unsigned short* __restrict__ Alo,
    const unsigned short* __restrict__ Wt, const float* __restrict__ bias,
    float* __restrict__ Yb,
    const unsigned* __restrict__ tbl, const int* __restrict__ rp_ar,
    const int* __restrict__ col, float* __restrict__ psum, int ngath,
    const float* __restrict__ xa_old, const float* __restrict__ Wl_a2c,
    unsigned short* __restrict__ ya_bf) {
    __shared__ float part[4][8][D];   // 16 KB (gather); combine uses 2 KB view
    int bid = blockIdx.x;
    if (bid < NGEMM) {
        // ---- gemm: Y = xc @ W + bias (two 32-row tiles per block) ----
        int tile = bid * 2 + (threadIdx.x >> 8);
        if (tile >= NROWT) return;
        int tid = threadIdx.x & 255;
        int wave = tid >> 6, lane = tid & 63;
        int cl = lane & 31, kh = lane >> 5;
        int n0 = wave * 32;
        int m0 = tile * 32;
        float bv = bias[n0 + cl];
        f32x16 acc;
#pragma unroll
        for (int qq = 0; qq < 16; qq++) acc[qq] = bv;
        {
            const unsigned short* Wlo_ = Wt + D * D;
            const unsigned short* ar = Ahi + (size_t)(m0 + cl) * D + kh * 8;
            const unsigned short* al = Alo + (size_t)(m0 + cl) * D + kh * 8;
            const unsigned short* wh = Wt + (size_t)(n0 + cl) * D + kh * 8;
            const unsigned short* wl = Wlo_ + (size_t)(n0 + cl) * D + kh * 8;
#pragma unroll
            for (int kc = 0; kc < 8; kc++) {
                bf16x8 ahi = *(const bf16x8*)(ar + kc * 16);
                bf16x8 alo = *(const bf16x8*)(al + kc * 16);
                bf16x8 bh = *(const bf16x8*)(wh + kc * 16);
                bf16x8 bl = *(const bf16x8*)(wl + kc * 16);
                acc = __builtin_amdgcn_mfma_f32_32x32x16_bf16(ahi, bh, acc, 0, 0, 0);
                acc = __builtin_amdgcn_mfma_f32_32x32x16_bf16(alo, bh, acc, 0, 0, 0);
                acc = __builtin_amdgcn_mfma_f32_32x32x16_bf16(ahi, bl, acc, 0, 0, 0);
            }
        }
        float* yb = Yb + (size_t)m0 * D + n0 + cl;
#pragma unroll
        for (int reg = 0; reg < 16; reg++) {
            int row = (reg & 3) + 8 * (reg >> 2) + 4 * kh;
            yb[(size_t)row * D] = acc[reg];
        }
    } else if (bid < NGEMM + ngath) {
        // ---- XCD-sliced mean gather (R10-exact body) ----
        int g = bid - NGEMM;
        int quad = g >> 3, r = g & 7;
        int tid = threadIdx.x;
        int a = tid >> 7;
        int sub = (tid >> 4) & 7;
        int sl = tid & 15;
        const uint4* tbl4 = (const uint4*)tbl;
        int agg = quad * 4 + a;
        int bin = agg * NRNG + r;
        int beg = rp_ar[bin], end = rp_ar[bin + 1];
        float f0 = 0, f1 = 0, f2 = 0, f3 = 0, f4 = 0, f5 = 0, f6 = 0, f7 = 0;
        int e = beg + sub;
        for (; e + 8 < end; e += 16) {
            int s0 = col[e];
            int s1 = col[e + 8];
            uint4 v0 = tbl4[(s0 << 4) + sl];
            uint4 v1 = tbl4[(s1 << 4) + sl];
            f0 += bf_lo(v0.x); f1 += bf_hi(v0.x); f2 += bf_lo(v0.y); f3 += bf_hi(v0.y);
            f4 += bf_lo(v0.z); f5 += bf_hi(v0.z); f6 += bf_lo(v0.w); f7 += bf_hi(v0.w);
            f0 += bf_lo(v1.x); f1 += bf_hi(v1.x); f2 += bf_lo(v1.y); f3 += bf_hi(v1.y);
            f4 += bf_lo(v1.z); f5 += bf_hi(v1.z); f6 += bf_lo(v1.w); f7 += bf_hi(v1.w);
        }
        if (e < end) {
            int s0 = col[e];
            uint4 v0 = tbl4[(s0 << 4) + sl];
            f0 += bf_lo(v0.x); f1 += bf_hi(v0.x); f2 += bf_lo(v0.y); f3 += bf_hi(v0.y);
            f4 += bf_lo(v0.z); f5 += bf_hi(v0.z); f6 += bf_lo(v0.w); f7 += bf_hi(v0.w);
        }
        float* pr = &part[a][sub][sl * 8];
        pr[0] = f0; pr[1] = f1; pr[2] = f2; pr[3] = f3;
        pr[4] = f4; pr[5] = f5; pr[6] = f6; pr[7] = f7;
        __syncthreads();
        int c = tid & 127;
        float s = 0.f;
#pragma unroll
        for (int gg = 0; gg < 8; gg++) s += part[a][gg][c];
        psum[((size_t)agg * NRNG + r) * D + c] = s;
    } else {
        // ---- combine-last (l==2 only): ya = bf16(xa_old @ Wl_a2c), 4 aggs/block ----
        int grp = threadIdx.x >> 7;
        int ab = (bid - NGEMM - ngath) * 4 + grp;   // exact grid: ab < NAGG always
        int j = threadIdx.x & 127;
        float* xr = &part[0][0][0] + grp * D;
        xr[j] = xa_old[ab * D + j];
        __syncthreads();
        float accy = 0.f;
#pragma unroll 4
        for (int k = 0; k < D; k++) accy += xr[k] * Wl_a2c[k * D + j];
        ya_bf[ab * D + j] = (unsigned short)bf16_rn(accy);
    }
}

// agg with LDS-staged ya (R10-proven). 256 blocks x 391 clients; ya halves staged
// in 144 KB LDS; chip ya traffic 410MB random -> 64MB sequential.
template <int LAST>
__global__ __launch_bounds__(1024) void agg_big(const unsigned short* __restrict__ ya,
                                                const int* __restrict__ rowptr,
                                                const int* __restrict__ col,
                                                const float* __restrict__ Yb,
                                                unsigned* __restrict__ xhi,
                                                unsigned* __restrict__ xlo,
                                                const float* __restrict__ Wlin,
                                                const float* __restrict__ blin,
                                                float* __restrict__ out) {
    __shared__ uint4 yast4[NAGG * 9];   // 144000 B: 1000 rows x (8 data + 1 pad) uint4
    int tid = threadIdx.x;
    int wave = tid >> 6, lane = tid & 63;
    int g = lane >> 3, q = lane & 7;    // 8 groups of 8 lanes per wave
    int m0 = blockIdx.x * CPB;
    const uint4* ya4g = (const uint4*)ya;   // 16 uint4 per row
    float dacc[4] = {0.f, 0.f, 0.f, 0.f};  // LAST partial dots, live across passes
#pragma unroll
    for (int h = 0; h < 2; h++) {
        if (h) __syncthreads();   // all waves done reading pass-0 LDS
        for (int i = tid; i < NAGG * 8; i += 1024) {
            int row = i >> 3, qq = i & 7;
            yast4[row * 9 + qq] = ya4g[(row << 4) + (h << 3) + qq];
        }
        __syncthreads();
#pragma unroll
        for (int cc = 0; cc < 4; cc++) {
            int c_local = (wave * 8 + g) * 4 + cc;   // 0..511
            int gid = m0 + c_local;
            bool act = (c_local < CPB) && (gid < NCLI);
            int beg = 0, end = 0;
            if (act) { beg = rowptr[gid]; end = rowptr[gid + 1]; }
            float s0 = 0, s1 = 0, s2 = 0, s3 = 0, s4 = 0, s5 = 0, s6 = 0, s7 = 0;
            for (int ch = beg; ch < end; ch += 8) {
                int ec = col[min(ch + q, end - 1)];
                int lim = min(8, end - ch);
#pragma unroll
                for (int j = 0; j < 8; j++) {
                    if (j < lim) {
                        int r = __shfl(ec, j, 8);
                        uint4 v = yast4[r * 9 + q];
                        s0 += bf_lo(v.x); s1 += bf_hi(v.x);
                        s2 += bf_lo(v.y); s3 += bf_hi(v.y);
                        s4 += bf_lo(v.z); s5 += bf_hi(v.z);
                        s6 += bf_lo(v.w); s7 += bf_hi(v.w);
                    }
                }
            }
            if (act) {
                float inv = 1.f / fmaxf((float)(end - beg), 1.f);
                const float4* yb4 =
                    (const float4*)(Yb + (size_t)gid * D + h * 64 + q * 8);
                float4 y0 = yb4[0], y1 = yb4[1];
                float r0 = leaky(y0.x + s0 * inv);
                float r1 = leaky(y0.y + s1 * inv);
                float r2 = leaky(y0.z + s2 * inv);
                float r3 = leaky(y0.w + s3 * inv);
                float r4 = leaky(y1.x + s4 * inv);
                float r5 = leaky(y1.y + s5 * inv);
                float r6 = leaky(y1.z + s6 * inv);
                float r7 = leaky(y1.w + s7 * inv);
                if (LAST) {
                    float4 w0 = *(const float4*)&Wlin[h * 64 + q * 8];
                    float4 w1 = *(const float4*)&Wlin[h * 64 + q * 8 + 4];
                    dacc[cc] += r0 * w0.x + r1 * w0.y + r2 * w0.z + r3 * w0.w +
                                r4 * w1.x + r5 * w1.y + r6 * w1.z + r7 * w1.w;
                    if (h == 1) {
                        float v = dacc[cc];
#pragma unroll
                        for (int off = 4; off > 0; off >>= 1) v += __shfl_down(v, off, 8);
                        if (q == 0) out[gid] = v + blin[0];
                    }
                } else {
                    unsigned h0 = bf16_rn(r0), h1 = bf16_rn(r1);
                    unsigned h2 = bf16_rn(r2), h3 = bf16_rn(r3);
                    unsigned h4 = bf16_rn(r4), h5 = bf16_rn(r5);
                    unsigned h6 = bf16_rn(r6), h7 = bf16_rn(r7);
                    uint4 hi, lo;
                    hi.x = h0 | (h1 << 16); hi.y = h2 | (h3 << 16);
                    hi.z = h4 | (h5 << 16); hi.w = h6 | (h7 << 16);
                    lo.x = pack_bf2(r0 - bf_val(h0), r1 - bf_val(h1));
                    lo.y = pack_bf2(r2 - bf_val(h2), r3 - bf_val(h3));
                    lo.z = pack_bf2(r4 - bf_val(h4), r5 - bf_val(h5));
                    lo.w = pack_bf2(r6 - bf_val(h6), r7 - bf_val(h7));
                    ((uint4*)xhi)[(gid << 4) + (h << 3) + q] = hi;
                    ((uint4*)xlo)[(gid << 4) + (h << 3) + q] = lo;
                }
            }
        }
    }
}

extern "C" void kernel_launch(void* const* d_in, const int* in_sizes, int n_in,
                              void* d_out, int out_size, void* d_ws, size_t ws_size,
                              hipStream_t stream) {
    const float* x_clients = (const float*)d_in[0];
    const float* x_agg     = (const float*)d_in[1];
    const int*   c2a_src   = (const int*)d_in[2];
    const int*   c2a_dst   = (const int*)d_in[3];
    const int*   a2c_src   = (const int*)d_in[4];
    const int*   a2c_dst   = (const int*)d_in[5];
    const float* Wl_c2a    = (const float*)d_in[6];
    const float* Wr_c2a    = (const float*)d_in[7];
    const float* b_c2a     = (const float*)d_in[8];
    const float* Wl_a2c    = (const float*)d_in[9];
    const float* Wr_a2c    = (const float*)d_in[10];
    const float* b_a2c     = (const float*)d_in[11];
    const float* W_lin     = (const float*)d_in[12];
    const float* b_lin     = (const float*)d_in[13];
    float* out = (float*)d_out;
    const int E = in_sizes[2];

    char* p = (char*)d_ws;
    auto alloc = [&](size_t bytes) {
        char* r = p;
        p += (bytes + 255) & ~(size_t)255;
        return r;
    };
    float*    Yb    = (float*)alloc(sizeof(float) * NCLI * D);         // gemm out; tmp1/2 early
    unsigned* xc_hi = (unsigned*)alloc(sizeof(unsigned) * NCLI * 64);  // bf16 hi (also gather tbl)
    unsigned* xc_lo = (unsigned*)alloc(sizeof(unsigned) * NCLI * 64);  // bf16 lo
    float*    xa    = (float*)alloc(sizeof(float) * NAGG * D);
    unsigned short* ya_bf = (unsigned short*)alloc(sizeof(unsigned short) * NAGG * D);
    unsigned short* Wt = (unsigned short*)alloc(sizeof(unsigned short) * NLAYER * 2 * D * D);
    float* psum  = (float*)alloc(sizeof(float) * NAGG * NRNG * D);     // 4 MB gather partials
    int* cnt_ar = (int*)alloc(sizeof(int) * (NBIN + NBKT));  // cnt_ar[0..7999] + bcnt
    int* bcnt  = cnt_ar + NBIN;
    int* rp_ar = (int*)alloc(sizeof(int) * (NBIN + 1));
    int* brp   = (int*)alloc(sizeof(int) * (NBKT + 1));
    int* bcur  = (int*)alloc(sizeof(int) * NBKT);
    int* ccur  = (int*)alloc(sizeof(int) * NC2A);
    int* rp_c  = (int*)alloc(sizeof(int) * (NCLI + 1));
    int* col_c2a = (int*)alloc(sizeof(int) * E);
    int* col_a2c = (int*)alloc(sizeof(int) * E);
    // tmp1/tmp2 alias Yb (12.8 MB needed, 51.2 MB available); lifetime ends before layers
    int* tmp1 = (int*)Yb;
    int* tmp2 = tmp1 + E;

    hipMemsetAsync(cnt_ar, 0, sizeof(int) * (NBIN + NBKT), stream);

    prep<<<NHIST + NCVTX + NCVTW, 256, 0, stream>>>(c2a_src, c2a_dst, a2c_dst, E, cnt_ar, bcnt,
                                                    (const float4*)x_clients,
                                                    (uint2*)xc_hi, (uint2*)xc_lo,
                                                    Wr_a2c, Wt);
    scan_both<<<2, 1024, 0, stream>>>(cnt_ar, rp_ar, bcnt, brp, bcur, ccur);
    scatter_coarse<<<512, 1024, 0, stream>>>(c2a_src, c2a_dst, a2c_src, a2c_dst, E,
                                             ccur, tmp1, bcur, tmp2);
    refine<<<NC2A + NBKT, 1024, 0, stream>>>(rp_ar, tmp1, col_c2a, brp, tmp2, rp_c, col_a2c);

    const float* xa_old = x_agg;
    for (int l = 0; l < NLAYER; l++) {
        if (l < NLAYER - 1) {
            // [gemm_y(l) || gather_mean(l)] in one launch (independent: both need only xc)
            layer_par<<<NGEMM + NGATH, 512, 0, stream>>>(
                (const unsigned short*)xc_hi, (const unsigned short*)xc_lo,
                Wt + l * 2 * D * D, b_a2c + l * D, Yb,
                xc_hi, rp_ar, col_c2a, psum, NGATH,
                xa_old, Wl_a2c + l * D * D, ya_bf);
            combine_agg<<<NAGG, 128, 0, stream>>>(psum, rp_ar, xa_old,
                                                  Wl_a2c + l * D * D, Wl_c2a + l * D * D,
                                                  Wr_c2a + l * D * D, b_c2a + l * D,
                                                  ya_bf, xa);
            agg_big<0><<<256, 1024, 0, stream>>>(ya_bf, rp_c, col_a2c, Yb,
                                                 xc_hi, xc_lo, nullptr, nullptr, nullptr);
        } else {
            // last layer: xa dead -> no gather; [gemm_y || combine<1>] in one launch
            layer_par<<<NGEMM + NLAST, 512, 0, stream>>>(
                (const unsigned short*)xc_hi, (const unsigned short*)xc_lo,
                Wt + l * 2 * D * D, b_a2c + l * D, Yb,
                xc_hi, rp_ar, col_c2a, psum, 0,
                xa_old, Wl_a2c + l * D * D, ya_bf);
            agg_big<1><<<256, 1024, 0, stream>>>(ya_bf, rp_c, col_a2c, Yb,
                                                 nullptr, nullptr, W_lin, b_lin, out);
        }
        xa_old = xa;
    }
}